// Round 1
// baseline (386.222 us; speedup 1.0000x reference)
//
#include <hip/hip_runtime.h>

typedef float floatx4 __attribute__((ext_vector_type(4)));
typedef __bf16 bf16x8 __attribute__((ext_vector_type(8)));
using u16 = unsigned short;
using u32 = unsigned int;

#define GLOBAL_AS __attribute__((address_space(1)))
#define LDS_AS    __attribute__((address_space(3)))

// ---------------- conversion: x fp32 -> bf16 (RNE) ----------------
__global__ void cvt_x_kernel(const float* __restrict__ x, u16* __restrict__ xb, int n8) {
  int stride = gridDim.x * blockDim.x;
  for (int i = blockIdx.x * blockDim.x + threadIdx.x; i < n8; i += stride) {
    const float4* p = (const float4*)(x + (size_t)i * 8);
    float4 a = p[0], b = p[1];
    float v[8] = {a.x, a.y, a.z, a.w, b.x, b.y, b.z, b.w};
    u32 r[8];
#pragma unroll
    for (int j = 0; j < 8; ++j) {
      u32 u = __float_as_uint(v[j]);
      r[j] = (u + 0x7FFFu + ((u >> 16) & 1u)) >> 16;  // round-to-nearest-even
    }
    uint4 o;
    o.x = r[0] | (r[1] << 16);
    o.y = r[2] | (r[3] << 16);
    o.z = r[4] | (r[5] << 16);
    o.w = r[6] | (r[7] << 16);
    *(uint4*)(xb + (size_t)i * 8) = o;
  }
}

// ---------------- quantize: w fp32 -> ternary {-1,0,+1} as bf16 bits ----------------
__global__ void quant_w_kernel(const float* __restrict__ w, u16* __restrict__ wb, int n8) {
  int stride = gridDim.x * blockDim.x;
  for (int i = blockIdx.x * blockDim.x + threadIdx.x; i < n8; i += stride) {
    const float4* p = (const float4*)(w + (size_t)i * 8);
    float4 a = p[0], b = p[1];
    float v[8] = {a.x, a.y, a.z, a.w, b.x, b.y, b.z, b.w};
    u32 r[8];
#pragma unroll
    for (int j = 0; j < 8; ++j) {
      r[j] = (v[j] > 0.05f) ? 0x3F80u : ((v[j] < -0.05f) ? 0xBF80u : 0u);
    }
    uint4 o;
    o.x = r[0] | (r[1] << 16);
    o.y = r[2] | (r[3] << 16);
    o.z = r[4] | (r[5] << 16);
    o.w = r[6] | (r[7] << 16);
    *(uint4*)(wb + (size_t)i * 8) = o;
  }
}

// ---------------- m97-structure 128x128 bf16 MFMA GEMM ----------------
// A: [M][K] bf16 (x), B: [N][K] bf16 (ternary W), C: [M][N] fp32, + bias[N]
// out[m][n] = sum_k A[m][k]*B[n][k] + bias[n]
__global__ __launch_bounds__(256) void gemm_bin_kernel(
    const u16* __restrict__ A, const u16* __restrict__ B,
    const float* __restrict__ bias, float* __restrict__ C,
    int M, int N, int K) {
  __shared__ u16 sA[128 * 32];
  __shared__ u16 sB[128 * 32];

  const int tid = threadIdx.x;
  const int w = tid >> 6;     // wave 0..3
  const int l = tid & 63;     // lane
  const int nbn = N >> 7;
  const int bm = blockIdx.x / nbn;
  const int bn = blockIdx.x % nbn;

  const int wr = w >> 1, wc = w & 1;   // 2x2 waves, each 64x64 output
  const int r = l & 15, g = l >> 4;

  floatx4 acc[4][4] = {};

  // staging: 256 threads stage 128x32 bf16 per tile; each thread 16B per chunk.
  // wave w, lane l -> row = c*64 + w*16 + (l>>2), k-part = (l&3)*8
  // LDS dest = (c*64 + w*16)*32 + l*8 elements  (wave-uniform base + lane*16B)
  const int srow = w * 16 + (l >> 2);
  const int skoff = (l & 3) * 8;
  const u16* Ag = A + (size_t)(bm * 128 + srow) * K + skoff;
  const u16* Bg = B + (size_t)(bn * 128 + srow) * K + skoff;
  u16* sAdst = sA + w * 16 * 32 + l * 8;
  u16* sBdst = sB + w * 16 * 32 + l * 8;

  for (int k0 = 0; k0 < K; k0 += 32) {
    __builtin_amdgcn_global_load_lds((const GLOBAL_AS void*)(Ag + k0),
                                     (LDS_AS void*)sAdst, 16, 0, 0);
    __builtin_amdgcn_global_load_lds((const GLOBAL_AS void*)(Ag + (size_t)64 * K + k0),
                                     (LDS_AS void*)(sAdst + 64 * 32), 16, 0, 0);
    __builtin_amdgcn_global_load_lds((const GLOBAL_AS void*)(Bg + k0),
                                     (LDS_AS void*)sBdst, 16, 0, 0);
    __builtin_amdgcn_global_load_lds((const GLOBAL_AS void*)(Bg + (size_t)64 * K + k0),
                                     (LDS_AS void*)(sBdst + 64 * 32), 16, 0, 0);
    __syncthreads();  // drains vmcnt(0) -> staged tiles visible

    bf16x8 af[4], bfr[4];
#pragma unroll
    for (int m = 0; m < 4; ++m)
      af[m] = *(const bf16x8*)(sA + (wr * 64 + m * 16 + r) * 32 + g * 8);
#pragma unroll
    for (int n = 0; n < 4; ++n)
      bfr[n] = *(const bf16x8*)(sB + (wc * 64 + n * 16 + r) * 32 + g * 8);
#pragma unroll
    for (int m = 0; m < 4; ++m)
#pragma unroll
      for (int n = 0; n < 4; ++n)
        acc[m][n] = __builtin_amdgcn_mfma_f32_16x16x32_bf16(af[m], bfr[n], acc[m][n], 0, 0, 0);
    __syncthreads();  // all reads done before next stage overwrites
  }

  // epilogue: C/D layout col = l&15, row = (l>>4)*4 + reg
  const int cbase = bn * 128 + wc * 64;
  float bv[4];
#pragma unroll
  for (int n = 0; n < 4; ++n) bv[n] = bias[cbase + n * 16 + r];
#pragma unroll
  for (int m = 0; m < 4; ++m) {
    const int rowb = bm * 128 + wr * 64 + m * 16 + g * 4;
#pragma unroll
    for (int n = 0; n < 4; ++n) {
      const int col = cbase + n * 16 + r;
#pragma unroll
      for (int q = 0; q < 4; ++q) {
        C[(size_t)(rowb + q) * N + col] = acc[m][n][q] + bv[n];
      }
    }
  }
}

// ---------------- fallback (ws too small / odd shapes): slow but correct ----------------
__global__ void gemm_naive_kernel(const float* __restrict__ x, const float* __restrict__ wgt,
                                  const float* __restrict__ bias, float* __restrict__ out,
                                  int M, int N, int K) {
  long long idx = (long long)blockIdx.x * blockDim.x + threadIdx.x;
  if (idx >= (long long)M * N) return;
  int o = (int)(idx % N);
  int m = (int)(idx / N);
  const float* xr = x + (size_t)m * K;
  const float* wr = wgt + (size_t)o * K;
  float s = 0.f;
  for (int i = 0; i < K; ++i) {
    float wv = wr[i];
    float t = (wv > 0.05f) ? 1.f : ((wv < -0.05f) ? -1.f : 0.f);
    s = fmaf(xr[i], t, s);
  }
  out[idx] = s + bias[o];
}

extern "C" void kernel_launch(void* const* d_in, const int* in_sizes, int n_in,
                              void* d_out, int out_size, void* d_ws, size_t ws_size,
                              hipStream_t stream) {
  const float* x    = (const float*)d_in[0];
  const float* wgt  = (const float*)d_in[1];
  const float* bias = (const float*)d_in[2];
  float* out = (float*)d_out;

  const int N = in_sizes[2];                 // 4096 (out features)
  const int K = in_sizes[1] / N;             // 4096 (in features)
  const int M = in_sizes[0] / K;             // 8192 (batch rows)

  const size_t need = ((size_t)M * K + (size_t)N * K) * sizeof(u16);
  if (ws_size >= need && (M % 128 == 0) && (N % 128 == 0) && (K % 32 == 0)) {
    u16* xb = (u16*)d_ws;
    u16* wb = xb + (size_t)M * K;
    const int nx8 = (M * K) / 8;
    const int nw8 = (N * K) / 8;
    cvt_x_kernel<<<2048, 256, 0, stream>>>(x, xb, nx8);
    quant_w_kernel<<<2048, 256, 0, stream>>>(wgt, wb, nw8);
    const int grid = (M / 128) * (N / 128);
    gemm_bin_kernel<<<grid, 256, 0, stream>>>(xb, wb, bias, out, M, N, K);
  } else {
    const long long total = (long long)M * N;
    gemm_naive_kernel<<<(unsigned)((total + 255) / 256), 256, 0, stream>>>(x, wgt, bias, out, M, N, K);
  }
}

// Round 2
// 319.263 us; speedup vs baseline: 1.2097x; 1.2097x over previous
//
#include <hip/hip_runtime.h>

typedef float floatx4 __attribute__((ext_vector_type(4)));
typedef __bf16 bf16x8 __attribute__((ext_vector_type(8)));
using u16 = unsigned short;
using u32 = unsigned int;

#define GLOBAL_AS __attribute__((address_space(1)))
#define LDS_AS    __attribute__((address_space(3)))

// ---------------- conversion: x fp32 -> bf16 (RNE) ----------------
__global__ void cvt_x_kernel(const float* __restrict__ x, u16* __restrict__ xb, int n8) {
  int stride = gridDim.x * blockDim.x;
  for (int i = blockIdx.x * blockDim.x + threadIdx.x; i < n8; i += stride) {
    const float4* p = (const float4*)(x + (size_t)i * 8);
    float4 a = p[0], b = p[1];
    float v[8] = {a.x, a.y, a.z, a.w, b.x, b.y, b.z, b.w};
    u32 r[8];
#pragma unroll
    for (int j = 0; j < 8; ++j) {
      u32 u = __float_as_uint(v[j]);
      r[j] = (u + 0x7FFFu + ((u >> 16) & 1u)) >> 16;  // RNE
    }
    uint4 o;
    o.x = r[0] | (r[1] << 16);
    o.y = r[2] | (r[3] << 16);
    o.z = r[4] | (r[5] << 16);
    o.w = r[6] | (r[7] << 16);
    *(uint4*)(xb + (size_t)i * 8) = o;
  }
}

// ---------------- quantize: w fp32 -> ternary {-1,0,+1} as bf16 bits ----------------
__global__ void quant_w_kernel(const float* __restrict__ w, u16* __restrict__ wb, int n8) {
  int stride = gridDim.x * blockDim.x;
  for (int i = blockIdx.x * blockDim.x + threadIdx.x; i < n8; i += stride) {
    const float4* p = (const float4*)(w + (size_t)i * 8);
    float4 a = p[0], b = p[1];
    float v[8] = {a.x, a.y, a.z, a.w, b.x, b.y, b.z, b.w};
    u32 r[8];
#pragma unroll
    for (int j = 0; j < 8; ++j) {
      r[j] = (v[j] > 0.05f) ? 0x3F80u : ((v[j] < -0.05f) ? 0xBF80u : 0u);
    }
    uint4 o;
    o.x = r[0] | (r[1] << 16);
    o.y = r[2] | (r[3] << 16);
    o.z = r[4] | (r[5] << 16);
    o.w = r[6] | (r[7] << 16);
    *(uint4*)(wb + (size_t)i * 8) = o;
  }
}

// ---------------- 256x256 8-phase bf16 MFMA GEMM (T1+T3+T4+T5) ----------------
// A: [M][K] bf16 (x), B: [N][K] bf16 (ternary W), out[m][n] = sum_k A[m][k]*B[n][k] + bias[n]
// 8 waves (2M x 4N), per-wave output 128x64. LDS: 4 ring slots of
// (A[256][32] + B[256][32]) bf16 = 4 x 32KB. Step = one K-half (32), 2 phases
// of 16 MFMA. Slot (s%4) holds step s data; restaged with step s+4 data during
// step s+1 (after death). Counted vmcnt(8) per step end; never 0 in steady state.
__global__ __launch_bounds__(512, 2) void gemm_bin_8ph(
    const u16* __restrict__ A, const u16* __restrict__ B,
    const float* __restrict__ bias, float* __restrict__ C,
    int M, int N, int K) {
  __shared__ u16 lds[65536];  // 128 KiB

  const int tid = threadIdx.x;
  const int w = tid >> 6, l = tid & 63;
  const int wr = w >> 2, wc = w & 3;       // 2x4 wave grid
  const int r = l & 15, g = l >> 4;

  const int nbn = N >> 8;
  int wg = blockIdx.x;
  const int nwg = gridDim.x;
  if ((nwg & 7) == 0) wg = (wg & 7) * (nwg >> 3) + (wg >> 3);  // XCD swizzle (bijective: nwg%8==0)
  const int bm = wg / nbn, bn = wg % nbn;

  const int NSTEPS = K >> 5;

  // staging: thread t covers row t>>2 (128 rows/chunk), k-elems (t&3)*8..+7
  const size_t Abase = (size_t)(bm * 256 + (tid >> 2)) * K + (tid & 3) * 8;
  const size_t Bbase = (size_t)(bn * 256 + (tid >> 2)) * K + (tid & 3) * 8;
  const size_t chunkStride = (size_t)128 * K;

  // LDS read bases (u16 elements); frag A m: +slot*16384 + m*512 ; frag B n: +slot*16384 + n*512
  const u16* const ldsA = lds + wr * 4096 + r * 32 + g * 8;
  const u16* const ldsB = lds + 8192 + wc * 2048 + r * 32 + g * 8;

  floatx4 acc[8][4] = {};

  // prologue: stage steps 0..3 into slots 0..3 (A0,A1,B0,B1 per slot)
  for (int u = 0; u < 4; ++u) {
    const int so = u * 16384;
    const u16* ga = A + Abase + (size_t)u * 32;
    const u16* gb = B + Bbase + (size_t)u * 32;
    __builtin_amdgcn_global_load_lds((const GLOBAL_AS void*)ga,
                                     (LDS_AS void*)(lds + so + tid * 8), 16, 0, 0);
    __builtin_amdgcn_global_load_lds((const GLOBAL_AS void*)(ga + chunkStride),
                                     (LDS_AS void*)(lds + so + 4096 + tid * 8), 16, 0, 0);
    __builtin_amdgcn_global_load_lds((const GLOBAL_AS void*)gb,
                                     (LDS_AS void*)(lds + so + 8192 + tid * 8), 16, 0, 0);
    __builtin_amdgcn_global_load_lds((const GLOBAL_AS void*)(gb + chunkStride),
                                     (LDS_AS void*)(lds + so + 12288 + tid * 8), 16, 0, 0);
  }
  asm volatile("s_waitcnt vmcnt(12)" ::: "memory");  // slot 0 landed
  __builtin_amdgcn_s_barrier();

  for (int s = 0; s < NSTEPS; ++s) {
    const int so = (s & 3) * 16384;
    const bool doSt = (s >= 1) && (s + 3 < NSTEPS);
    const int son = ((s + 3) & 3) * 16384;
    const u16* gaN = A + Abase + (size_t)(s + 3) * 32;
    const u16* gbN = B + Bbase + (size_t)(s + 3) * 32;

    // ---- phase A: read A frags + B n0,n1; stage next A-part; 16 MFMA ----
    bf16x8 af[8], bf0, bf1, bf2, bf3;
#pragma unroll
    for (int m = 0; m < 8; ++m) af[m] = *(const bf16x8*)(ldsA + so + m * 512);
    bf0 = *(const bf16x8*)(ldsB + so + 0 * 512);
    bf1 = *(const bf16x8*)(ldsB + so + 1 * 512);
    if (doSt) {
      __builtin_amdgcn_global_load_lds((const GLOBAL_AS void*)gaN,
                                       (LDS_AS void*)(lds + son + tid * 8), 16, 0, 0);
      __builtin_amdgcn_global_load_lds((const GLOBAL_AS void*)(gaN + chunkStride),
                                       (LDS_AS void*)(lds + son + 4096 + tid * 8), 16, 0, 0);
    }
    __builtin_amdgcn_s_barrier();
    asm volatile("s_waitcnt lgkmcnt(0)" ::: "memory");
    __builtin_amdgcn_sched_barrier(0);  // rule #18: keep MFMA below the wait
    __builtin_amdgcn_s_setprio(1);
#pragma unroll
    for (int m = 0; m < 8; ++m) {
      acc[m][0] = __builtin_amdgcn_mfma_f32_16x16x32_bf16(af[m], bf0, acc[m][0], 0, 0, 0);
      acc[m][1] = __builtin_amdgcn_mfma_f32_16x16x32_bf16(af[m], bf1, acc[m][1], 0, 0, 0);
    }
    __builtin_amdgcn_s_setprio(0);
    __builtin_amdgcn_s_barrier();

    // ---- phase B: read B n2,n3; stage next B-part; 16 MFMA; counted vmcnt ----
    bf2 = *(const bf16x8*)(ldsB + so + 2 * 512);
    bf3 = *(const bf16x8*)(ldsB + so + 3 * 512);
    if (doSt) {
      __builtin_amdgcn_global_load_lds((const GLOBAL_AS void*)gbN,
                                       (LDS_AS void*)(lds + son + 8192 + tid * 8), 16, 0, 0);
      __builtin_amdgcn_global_load_lds((const GLOBAL_AS void*)(gbN + chunkStride),
                                       (LDS_AS void*)(lds + son + 12288 + tid * 8), 16, 0, 0);
    }
    __builtin_amdgcn_s_barrier();
    asm volatile("s_waitcnt lgkmcnt(0)" ::: "memory");
    __builtin_amdgcn_sched_barrier(0);
    __builtin_amdgcn_s_setprio(1);
#pragma unroll
    for (int m = 0; m < 8; ++m) {
      acc[m][2] = __builtin_amdgcn_mfma_f32_16x16x32_bf16(af[m], bf2, acc[m][2], 0, 0, 0);
      acc[m][3] = __builtin_amdgcn_mfma_f32_16x16x32_bf16(af[m], bf3, acc[m][3], 0, 0, 0);
    }
    __builtin_amdgcn_s_setprio(0);
    if (s + 1 < NSTEPS) {
      if (s + 3 < NSTEPS)      asm volatile("s_waitcnt vmcnt(8)" ::: "memory");
      else if (s + 2 < NSTEPS) asm volatile("s_waitcnt vmcnt(4)" ::: "memory");
      else                     asm volatile("s_waitcnt vmcnt(0)" ::: "memory");
      __builtin_amdgcn_s_barrier();
    }
  }

  // ---- epilogue: C/D layout col = l&15, row = (l>>4)*4 + q (m89/m91-verified) ----
  const int colb = bn * 256 + wc * 64;
  float bv[4];
#pragma unroll
  for (int n = 0; n < 4; ++n) bv[n] = bias[colb + n * 16 + r];
  const int rowb0 = bm * 256 + wr * 128;
#pragma unroll
  for (int m = 0; m < 8; ++m) {
    const int rowb = rowb0 + m * 16 + g * 4;
#pragma unroll
    for (int n = 0; n < 4; ++n) {
      const int col = colb + n * 16 + r;
      float* cp = C + (size_t)rowb * N + col;
#pragma unroll
      for (int q = 0; q < 4; ++q) cp[(size_t)q * N] = acc[m][n][q] + bv[n];
    }
  }
}

// ---------------- fallback: slow but correct ----------------
__global__ void gemm_naive_kernel(const float* __restrict__ x, const float* __restrict__ wgt,
                                  const float* __restrict__ bias, float* __restrict__ out,
                                  int M, int N, int K) {
  long long idx = (long long)blockIdx.x * blockDim.x + threadIdx.x;
  if (idx >= (long long)M * N) return;
  int o = (int)(idx % N);
  int m = (int)(idx / N);
  const float* xr = x + (size_t)m * K;
  const float* wr = wgt + (size_t)o * K;
  float s = 0.f;
  for (int i = 0; i < K; ++i) {
    float wv = wr[i];
    float t = (wv > 0.05f) ? 1.f : ((wv < -0.05f) ? -1.f : 0.f);
    s = fmaf(xr[i], t, s);
  }
  out[idx] = s + bias[o];
}

extern "C" void kernel_launch(void* const* d_in, const int* in_sizes, int n_in,
                              void* d_out, int out_size, void* d_ws, size_t ws_size,
                              hipStream_t stream) {
  const float* x    = (const float*)d_in[0];
  const float* wgt  = (const float*)d_in[1];
  const float* bias = (const float*)d_in[2];
  float* out = (float*)d_out;

  const int N = in_sizes[2];                 // out features
  const int K = in_sizes[1] / N;             // in features
  const int M = in_sizes[0] / K;             // batch rows

  const size_t need = ((size_t)M * K + (size_t)N * K) * sizeof(u16);
  if (ws_size >= need && (M % 256 == 0) && (N % 256 == 0) && (K % 32 == 0) && K >= 128) {
    u16* xb = (u16*)d_ws;
    u16* wb = xb + (size_t)M * K;
    const int nx8 = (M * K) / 8;
    const int nw8 = (N * K) / 8;
    cvt_x_kernel<<<2048, 256, 0, stream>>>(x, xb, nx8);
    quant_w_kernel<<<2048, 256, 0, stream>>>(wgt, wb, nw8);
    const int grid = (M / 256) * (N / 256);
    gemm_bin_8ph<<<grid, 512, 0, stream>>>(xb, wb, bias, out, M, N, K);
  } else {
    const long long total = (long long)M * N;
    gemm_naive_kernel<<<(unsigned)((total + 255) / 256), 256, 0, stream>>>(x, wgt, bias, out, M, N, K);
  }
}

// Round 3
// 314.026 us; speedup vs baseline: 1.2299x; 1.0167x over previous
//
#include <hip/hip_runtime.h>

typedef float floatx4 __attribute__((ext_vector_type(4)));
typedef __bf16 bf16x8 __attribute__((ext_vector_type(8)));
using u16 = unsigned short;
using u32 = unsigned int;

#define GLOBAL_AS __attribute__((address_space(1)))
#define LDS_AS    __attribute__((address_space(3)))

// ---------------- conversion: x fp32 -> bf16 (RNE) ----------------
__global__ void cvt_x_kernel(const float* __restrict__ x, u16* __restrict__ xb, int n8) {
  int stride = gridDim.x * blockDim.x;
  for (int i = blockIdx.x * blockDim.x + threadIdx.x; i < n8; i += stride) {
    const float4* p = (const float4*)(x + (size_t)i * 8);
    float4 a = p[0], b = p[1];
    float v[8] = {a.x, a.y, a.z, a.w, b.x, b.y, b.z, b.w};
    u32 r[8];
#pragma unroll
    for (int j = 0; j < 8; ++j) {
      u32 u = __float_as_uint(v[j]);
      r[j] = (u + 0x7FFFu + ((u >> 16) & 1u)) >> 16;  // RNE
    }
    uint4 o;
    o.x = r[0] | (r[1] << 16);
    o.y = r[2] | (r[3] << 16);
    o.z = r[4] | (r[5] << 16);
    o.w = r[6] | (r[7] << 16);
    *(uint4*)(xb + (size_t)i * 8) = o;
  }
}

// ---------------- quantize: w fp32 -> ternary {-1,0,+1} as bf16 bits ----------------
__global__ void quant_w_kernel(const float* __restrict__ w, u16* __restrict__ wb, int n8) {
  int stride = gridDim.x * blockDim.x;
  for (int i = blockIdx.x * blockDim.x + threadIdx.x; i < n8; i += stride) {
    const float4* p = (const float4*)(w + (size_t)i * 8);
    float4 a = p[0], b = p[1];
    float v[8] = {a.x, a.y, a.z, a.w, b.x, b.y, b.z, b.w};
    u32 r[8];
#pragma unroll
    for (int j = 0; j < 8; ++j) {
      r[j] = (v[j] > 0.05f) ? 0x3F80u : ((v[j] < -0.05f) ? 0xBF80u : 0u);
    }
    uint4 o;
    o.x = r[0] | (r[1] << 16);
    o.y = r[2] | (r[3] << 16);
    o.z = r[4] | (r[5] << 16);
    o.w = r[6] | (r[7] << 16);
    *(uint4*)(wb + (size_t)i * 8) = o;
  }
}

// ---------------- 256x256 8-phase bf16 MFMA GEMM ----------------
// A: [M][K] bf16 (x), B: [N][K] bf16 (ternary W), out[m][n] = sum_k A[m][k]*B[n][k] + bias[n]
// 8 waves (2M x 4N). LDS: 4 ring slots of (A[256][32] + B[256][32]) = 4 x 32KB.
// FRAGMENT-PERMUTED LDS: within each 8KB chunk (128 rows x K=32), the 1KB
// block for 16-row group m stores lane-l's MFMA fragment at byte m*1024+l*16
// (l = g*16+r -> row m*16+r, k-part g*8). Achieved by permuting the GLOBAL
// source address (LDS dest stays linear, global_load_lds-compatible; read is
// wave_base + m*1024 + lane*16 -> zero bank conflicts: each 8-lane group
// covers all 32 banks).
__global__ __launch_bounds__(512, 2) void gemm_bin_8ph(
    const u16* __restrict__ A, const u16* __restrict__ B,
    const float* __restrict__ bias, float* __restrict__ C,
    int M, int N, int K) {
  __shared__ u16 lds[65536];  // 128 KiB

  const int tid = threadIdx.x;
  const int w = tid >> 6, l = tid & 63;
  const int wr = w >> 2, wc = w & 3;       // 2x4 wave grid
  const int r = l & 15;

  const int nbn = N >> 8;
  int wg = blockIdx.x;
  const int nwg = gridDim.x;
  if ((nwg & 7) == 0) wg = (wg & 7) * (nwg >> 3) + (wg >> 3);  // XCD swizzle (bijective: nwg%8==0)
  const int bm = wg / nbn, bn = wg % nbn;

  const int NSTEPS = K >> 5;

  // staging source (fragment-permuted): thread t -> row 16*(t>>6)+(t&15),
  // k-elems 8*((t>>4)&3) .. +7 within the step's K=32 window.
  const int prow = ((tid >> 6) << 4) + (tid & 15);
  const int pk = ((tid >> 4) & 3) << 3;
  const size_t Abase = (size_t)(bm * 256 + prow) * K + pk;
  const size_t Bbase = (size_t)(bn * 256 + prow) * K + pk;
  const size_t chunkStride = (size_t)128 * K;

  // LDS read bases (u16 elems): lane-sequential l*8 (=16B/lane)
  // A frag m: wr*4096 + m*512 ; B frag n: 8192 + wc*2048 + n*512
  const u16* const ldsA = lds + wr * 4096 + l * 8;
  const u16* const ldsB = lds + 8192 + wc * 2048 + l * 8;

  floatx4 acc[8][4] = {};

  // prologue: stage steps 0..3 into slots 0..3
  for (int u = 0; u < 4; ++u) {
    const int so = u * 16384;
    const u16* ga = A + Abase + (size_t)u * 32;
    const u16* gb = B + Bbase + (size_t)u * 32;
    __builtin_amdgcn_global_load_lds((const GLOBAL_AS void*)ga,
                                     (LDS_AS void*)(lds + so + tid * 8), 16, 0, 0);
    __builtin_amdgcn_global_load_lds((const GLOBAL_AS void*)(ga + chunkStride),
                                     (LDS_AS void*)(lds + so + 4096 + tid * 8), 16, 0, 0);
    __builtin_amdgcn_global_load_lds((const GLOBAL_AS void*)gb,
                                     (LDS_AS void*)(lds + so + 8192 + tid * 8), 16, 0, 0);
    __builtin_amdgcn_global_load_lds((const GLOBAL_AS void*)(gb + chunkStride),
                                     (LDS_AS void*)(lds + so + 12288 + tid * 8), 16, 0, 0);
  }
  asm volatile("s_waitcnt vmcnt(12)" ::: "memory");  // slot 0 landed
  __builtin_amdgcn_s_barrier();

  for (int s = 0; s < NSTEPS; ++s) {
    const int so = (s & 3) * 16384;
    const bool doSt = (s >= 1) && (s + 3 < NSTEPS);
    const int son = ((s + 3) & 3) * 16384;
    const u16* gaN = A + Abase + (size_t)(s + 3) * 32;
    const u16* gbN = B + Bbase + (size_t)(s + 3) * 32;

    // ---- phase A: read af[0..3] + bf[0..3] (8 reads); stage next A; MFMA m0..3 x n0..3 ----
    bf16x8 af[8], bf[4];
#pragma unroll
    for (int m = 0; m < 4; ++m) af[m] = *(const bf16x8*)(ldsA + so + m * 512);
#pragma unroll
    for (int n = 0; n < 4; ++n) bf[n] = *(const bf16x8*)(ldsB + so + n * 512);
    if (doSt) {
      __builtin_amdgcn_global_load_lds((const GLOBAL_AS void*)gaN,
                                       (LDS_AS void*)(lds + son + tid * 8), 16, 0, 0);
      __builtin_amdgcn_global_load_lds((const GLOBAL_AS void*)(gaN + chunkStride),
                                       (LDS_AS void*)(lds + son + 4096 + tid * 8), 16, 0, 0);
    }
    __builtin_amdgcn_s_barrier();
    asm volatile("s_waitcnt lgkmcnt(0)" ::: "memory");
    __builtin_amdgcn_sched_barrier(0);  // rule #18
    __builtin_amdgcn_s_setprio(1);
#pragma unroll
    for (int m = 0; m < 4; ++m)
#pragma unroll
      for (int n = 0; n < 4; ++n)
        acc[m][n] = __builtin_amdgcn_mfma_f32_16x16x32_bf16(af[m], bf[n], acc[m][n], 0, 0, 0);
    __builtin_amdgcn_s_setprio(0);
    __builtin_amdgcn_s_barrier();

    // ---- phase B: read af[4..7] (4 reads); stage next B; MFMA m4..7 x n0..3 ----
#pragma unroll
    for (int m = 4; m < 8; ++m) af[m] = *(const bf16x8*)(ldsA + so + m * 512);
    if (doSt) {
      __builtin_amdgcn_global_load_lds((const GLOBAL_AS void*)gbN,
                                       (LDS_AS void*)(lds + son + 8192 + tid * 8), 16, 0, 0);
      __builtin_amdgcn_global_load_lds((const GLOBAL_AS void*)(gbN + chunkStride),
                                       (LDS_AS void*)(lds + son + 12288 + tid * 8), 16, 0, 0);
    }
    __builtin_amdgcn_s_barrier();
    asm volatile("s_waitcnt lgkmcnt(0)" ::: "memory");
    __builtin_amdgcn_sched_barrier(0);
    __builtin_amdgcn_s_setprio(1);
#pragma unroll
    for (int m = 4; m < 8; ++m)
#pragma unroll
      for (int n = 0; n < 4; ++n)
        acc[m][n] = __builtin_amdgcn_mfma_f32_16x16x32_bf16(af[m], bf[n], acc[m][n], 0, 0, 0);
    __builtin_amdgcn_s_setprio(0);
    if (s + 1 < NSTEPS) {
      if (s + 3 < NSTEPS)      asm volatile("s_waitcnt vmcnt(8)" ::: "memory");
      else if (s + 2 < NSTEPS) asm volatile("s_waitcnt vmcnt(4)" ::: "memory");
      else                     asm volatile("s_waitcnt vmcnt(0)" ::: "memory");
      __builtin_amdgcn_s_barrier();
    }
  }

  // ---- epilogue: C/D layout col = l&15, row = (l>>4)*4 + q (m89/m91-verified) ----
  const int g = l >> 4;
  const int colb = bn * 256 + wc * 64;
  float bv[4];
#pragma unroll
  for (int n = 0; n < 4; ++n) bv[n] = bias[colb + n * 16 + r];
  const int rowb0 = bm * 256 + wr * 128;
#pragma unroll
  for (int m = 0; m < 8; ++m) {
    const int rowb = rowb0 + m * 16 + g * 4;
#pragma unroll
    for (int n = 0; n < 4; ++n) {
      const int col = colb + n * 16 + r;
      float* cp = C + (size_t)rowb * N + col;
#pragma unroll
      for (int q = 0; q < 4; ++q) cp[(size_t)q * N] = acc[m][n][q] + bv[n];
    }
  }
}

// ---------------- fallback: slow but correct ----------------
__global__ void gemm_naive_kernel(const float* __restrict__ x, const float* __restrict__ wgt,
                                  const float* __restrict__ bias, float* __restrict__ out,
                                  int M, int N, int K) {
  long long idx = (long long)blockIdx.x * blockDim.x + threadIdx.x;
  if (idx >= (long long)M * N) return;
  int o = (int)(idx % N);
  int m = (int)(idx / N);
  const float* xr = x + (size_t)m * K;
  const float* wr = wgt + (size_t)o * K;
  float s = 0.f;
  for (int i = 0; i < K; ++i) {
    float wv = wr[i];
    float t = (wv > 0.05f) ? 1.f : ((wv < -0.05f) ? -1.f : 0.f);
    s = fmaf(xr[i], t, s);
  }
  out[idx] = s + bias[o];
}

extern "C" void kernel_launch(void* const* d_in, const int* in_sizes, int n_in,
                              void* d_out, int out_size, void* d_ws, size_t ws_size,
                              hipStream_t stream) {
  const float* x    = (const float*)d_in[0];
  const float* wgt  = (const float*)d_in[1];
  const float* bias = (const float*)d_in[2];
  float* out = (float*)d_out;

  const int N = in_sizes[2];                 // out features
  const int K = in_sizes[1] / N;             // in features
  const int M = in_sizes[0] / K;             // batch rows

  const size_t need = ((size_t)M * K + (size_t)N * K) * sizeof(u16);
  if (ws_size >= need && (M % 256 == 0) && (N % 256 == 0) && (K % 32 == 0) && K >= 128) {
    u16* xb = (u16*)d_ws;
    u16* wb = xb + (size_t)M * K;
    const int nx8 = (M * K) / 8;
    const int nw8 = (N * K) / 8;
    cvt_x_kernel<<<2048, 256, 0, stream>>>(x, xb, nx8);
    quant_w_kernel<<<2048, 256, 0, stream>>>(wgt, wb, nw8);
    const int grid = (M / 256) * (N / 256);
    gemm_bin_8ph<<<grid, 512, 0, stream>>>(xb, wb, bias, out, M, N, K);
  } else {
    const long long total = (long long)M * N;
    gemm_naive_kernel<<<(unsigned)((total + 255) / 256), 256, 0, stream>>>(x, wgt, bias, out, M, N, K);
  }
}